// Round 8
// baseline (152.175 us; speedup 1.0000x reference)
//
#include <hip/hip_runtime.h>

#define BB 2
#define HH 1024
#define WW 1024
#define MU 5

__device__ __forceinline__ float fast_rcp(float x) { return __builtin_amdgcn_rcpf(x); }
__device__ __forceinline__ float fast_rsq(float x) { return __builtin_amdgcn_rsqf(x); }

// ---------------------------------------------------------------------------
// Kernel 1: Sobel + init tangent (interleaved (B,H,W)·float2) + raw mag + block max.
// ---------------------------------------------------------------------------
#define SR 8
__global__ __launch_bounds__(256) void sobel_init(
    const float* __restrict__ x,
    float2* __restrict__ tf,         // (B,H,W) float2
    float* __restrict__ mag,         // (B,H,W) raw
    float* __restrict__ block_max)   // 1024
{
    __shared__ float xs[SR + 2][264];
    const int t = threadIdx.x;
    const int w0 = blockIdx.x * 256;
    const int h0 = blockIdx.y * SR;
    const int b = blockIdx.z;
    const size_t plane = (size_t)HH * WW;
    const float* xb = x + (size_t)b * plane;

    for (int i = t; i < (SR + 2) * 66; i += 256) {
        int r = i / 66, c4 = i % 66;
        int g = h0 - 1 + r;
        int gw = w0 - 4 + 4 * c4;
        float4 v = make_float4(0.f, 0.f, 0.f, 0.f);
        if (g >= 0 && g < HH && gw >= 0 && gw < WW)
            v = *(const float4*)(xb + (size_t)g * WW + gw);
        *(float4*)&xs[r][4 * c4] = v;
    }
    __syncthreads();

    float lmax = 0.f;
    const int c = 4 + t;
    #pragma unroll
    for (int k = 0; k < SR; ++k) {
        const float* rT = xs[k], * rM = xs[k + 1], * rB = xs[k + 2];
        float tl = rT[c - 1], tc = rT[c], tr = rT[c + 1];
        float ml = rM[c - 1],             mr = rM[c + 1];
        float bl = rB[c - 1], bc = rB[c], br = rB[c + 1];
        float s0 = (bl - tl) + 2.f * (bc - tc) + (br - tr);   // k
        float s1 = (tr - tl) + 2.f * (mr - ml) + (br - bl);   // k^T
        float m = sqrtf(fmaf(s0, s0, s1 * s1));
        float inv = (m == 0.f) ? 1.f : fast_rcp(m);
        size_t gi = (size_t)(h0 + k) * WW + (w0 + t);
        mag[(size_t)b * plane + gi] = m;
        tf[(size_t)b * plane + gi] = make_float2(-s1 * inv, s0 * inv);
        lmax = fmaxf(lmax, m);
    }

    #pragma unroll
    for (int off = 32; off; off >>= 1) lmax = fmaxf(lmax, __shfl_down(lmax, off, 64));
    __shared__ float smax[4];
    if ((t & 63) == 0) smax[t >> 6] = lmax;
    __syncthreads();
    if (t == 0)
        block_max[(blockIdx.z * 128 + blockIdx.y) * 4 + blockIdx.x] =
            fmaxf(fmaxf(smax[0], smax[1]), fmaxf(smax[2], smax[3]));
}

// ---------------------------------------------------------------------------
// Kernel 2: reduce 1024 per-block maxes -> gmax.
// ---------------------------------------------------------------------------
__global__ __launch_bounds__(256) void reduce_max(
    const float* __restrict__ block_max, float* __restrict__ gmax)
{
    const int t = threadIdx.x;
    float m = 0.f;
    #pragma unroll
    for (int i = 0; i < 4; ++i) m = fmaxf(m, block_max[t + 256 * i]);
    #pragma unroll
    for (int off = 32; off; off >>= 1) m = fmaxf(m, __shfl_down(m, off, 64));
    __shared__ float smax[4];
    if ((t & 63) == 0) smax[t >> 6] = m;
    __syncthreads();
    if (t == 0) gmax[0] = fmaxf(fmaxf(smax[0], smax[1]), fmaxf(smax[2], smax[3]));
}

// ---------------------------------------------------------------------------
// Kernel 3: mag -> em = exp(-2*mag/max), in place (once; amortized over 6 passes).
// Weight identity: (tanh(my-mx)+1)/2 == 1/(1 + em_y/em_x).
// ---------------------------------------------------------------------------
__global__ __launch_bounds__(256) void mag2em(
    float* __restrict__ mag, const float* __restrict__ gmax)
{
    const float s = 2.f * fast_rcp(gmax[0]);
    const int i = blockIdx.x * 256 + threadIdx.x;
    float4* p = (float4*)mag + i;
    float4 v = *p;
    v.x = __expf(-s * v.x);
    v.y = __expf(-s * v.y);
    v.z = __expf(-s * v.z);
    v.w = __expf(-s * v.w);
    *p = v;
}

// ---------------------------------------------------------------------------
// Kernel 4: VERTICAL pass — NO LDS, NO BARRIERS. Thread owns an 8-row column
// strip; sliding 18-row register window loaded directly from global (lane=col
// -> coalesced). Halo re-reads (2.25x) absorbed by L3. OOB: tang=0, em=1
// (exact zero-pad semantics; normalize(0)=0 matches mag==0 guard).
// ---------------------------------------------------------------------------
#define VSTRIP 8
__global__ __launch_bounds__(256) void etf_v(
    const float2* __restrict__ tin, float2* __restrict__ tout,
    const float* __restrict__ em)
{
    const int c  = blockIdx.x * 256 + threadIdx.x;
    const int r0 = blockIdx.y * VSTRIP;
    const int b  = blockIdx.z;
    const size_t plane = (size_t)HH * WW;
    const float2* tb = tin + (size_t)b * plane;
    const float*  eb = em  + (size_t)b * plane;

    float w0[VSTRIP + 10], w1[VSTRIP + 10], we[VSTRIP + 10];
    #pragma unroll
    for (int j = 0; j < 10; ++j) {            // rows r0-5 .. r0+4 (g<HH always)
        int g = r0 - MU + j;
        float2 v = make_float2(0.f, 0.f); float e = 1.f;
        if (g >= 0) { v = tb[(size_t)g * WW + c]; e = eb[(size_t)g * WW + c]; }
        w0[j] = v.x; w1[j] = v.y; we[j] = e;
    }
    #pragma unroll
    for (int i = 0; i < VSTRIP; ++i) {
        int g = r0 + i + MU;                  // g>=5 always; guard top only
        float2 v = make_float2(0.f, 0.f); float e = 1.f;
        if (g < HH) { v = tb[(size_t)g * WW + c]; e = eb[(size_t)g * WW + c]; }
        w0[i + 10] = v.x; w1[i + 10] = v.y; we[i + 10] = e;

        float tx0 = w0[i + MU], tx1 = w1[i + MU];
        float remx = fast_rcp(we[i + MU]);
        float a0 = 0.f, a1 = 0.f;
        #pragma unroll
        for (int d = 0; d <= 2 * MU; ++d) {
            float s = fast_rcp(fmaf(we[i + d], remx, 1.f));   // (tanh(my-mx)+1)/2
            float w = s * fmaf(tx0, w0[i + d], tx1 * w1[i + d]);
            a0 = fmaf(w0[i + d], w, a0);
            a1 = fmaf(w1[i + d], w, a1);
        }
        float n2 = fmaf(a0, a0, a1 * a1);
        float inv = (n2 == 0.f) ? 1.f : fast_rsq(n2);
        tout[(size_t)b * plane + (size_t)(r0 + i) * WW + c] = make_float2(a0 * inv, a1 * inv);
    }
}

// ---------------------------------------------------------------------------
// Kernel 5: HORIZONTAL pass — ONE barrier. Stage 32 rows x 80 cols (8-col halo)
// into LDS (tang stride 81 float2, em stride 83: conflict-free), barrier,
// register-window compute (thread = row x 8-col group), write DIRECTLY to
// global (per-lane 64B-contiguous; block covers full lines -> L2 combines).
// LDS = 20736 + 10624 = 31360 B -> 5 blocks/CU.
// ---------------------------------------------------------------------------
template <int PLANAR_OUT>
__global__ __launch_bounds__(256) void etf_h(
    const float2* __restrict__ tin, float* __restrict__ tout,
    const float* __restrict__ em)
{
    __shared__ float2 sT[32][81];
    __shared__ float  sE[32][83];
    const int t = threadIdx.x;
    const int w0 = blockIdx.x * 64;
    const int h0 = blockIdx.y * 32;
    const int b = blockIdx.z;
    const size_t plane = (size_t)HH * WW;
    const float2* tb = tin + (size_t)b * plane;
    const float*  eb = em  + (size_t)b * plane;

    // stage: tang 32x40 float4 (2px) chunks; em 32x20 float4 (4px) chunks
    for (int i = t; i < 1920; i += 256) {
        if (i < 1280) {
            int r = i / 40, c4 = i % 40;
            int gw = w0 - 8 + 2 * c4;                 // even; chunks never straddle edge
            float4 v = make_float4(0.f, 0.f, 0.f, 0.f);
            if (gw >= 0 && gw < WW)
                v = *(const float4*)(tb + (size_t)(h0 + r) * WW + gw);
            sT[r][c4 * 2]     = make_float2(v.x, v.y);
            sT[r][c4 * 2 + 1] = make_float2(v.z, v.w);
        } else {
            int j = i - 1280;
            int r = j / 20, c4 = j % 20;
            int gw = w0 - 8 + 4 * c4;
            float4 v = make_float4(1.f, 1.f, 1.f, 1.f);   // OOB em = 1
            if (gw >= 0 && gw < WW)
                v = *(const float4*)(eb + (size_t)(h0 + r) * WW + gw);
            sE[r][4 * c4] = v.x; sE[r][4 * c4 + 1] = v.y;
            sE[r][4 * c4 + 2] = v.z; sE[r][4 * c4 + 3] = v.w;
        }
    }
    __syncthreads();

    const int r  = t & 31;
    const int cg = t >> 5;
    const int cb = 8 + cg * 8;                 // staged col of first center
    float h0a[18], h1a[18], hea[18];
    #pragma unroll
    for (int j = 0; j < 18; ++j) {             // staged cols 3..76, in range
        float2 v = sT[r][cb - MU + j];
        h0a[j] = v.x; h1a[j] = v.y;
        hea[j] = sE[r][cb - MU + j];
    }

    #pragma unroll
    for (int k = 0; k < 8; ++k) {
        float tx0 = h0a[k + MU], tx1 = h1a[k + MU];
        float remx = fast_rcp(hea[k + MU]);
        float a0 = 0.f, a1 = 0.f;
        #pragma unroll
        for (int d = 0; d <= 2 * MU; ++d) {
            float s = fast_rcp(fmaf(hea[k + d], remx, 1.f));
            float w = s * fmaf(tx0, h0a[k + d], tx1 * h1a[k + d]);
            a0 = fmaf(h0a[k + d], w, a0);
            a1 = fmaf(h1a[k + d], w, a1);
        }
        float n2 = fmaf(a0, a0, a1 * a1);
        float inv = (n2 == 0.f) ? 1.f : fast_rsq(n2);
        size_t gi = (size_t)(h0 + r) * WW + (w0 + cg * 8 + k);
        if (PLANAR_OUT) {
            tout[(size_t)(2 * b)     * plane + gi] = a0 * inv;
            tout[(size_t)(2 * b + 1) * plane + gi] = a1 * inv;
        } else {
            ((float2*)tout)[(size_t)b * plane + gi] = make_float2(a0 * inv, a1 * inv);
        }
    }
}

extern "C" void kernel_launch(void* const* d_in, const int* in_sizes, int n_in,
                              void* d_out, int out_size, void* d_ws, size_t ws_size,
                              hipStream_t stream)
{
    const float* x = (const float*)d_in[0];   // (2,1,1024,1024) fp32
    char* ws = (char*)d_ws;
    const size_t plane = (size_t)HH * WW;

    float2* tfA = (float2*)ws;                                          // 16 MB
    float2* tfB = (float2*)(ws + sizeof(float) * BB * 2 * plane);       // 16 MB
    float* mag  = (float*)(ws + sizeof(float) * BB * 4 * plane);        // 8 MB (becomes em)
    float* gmax = (float*)(ws + sizeof(float) * BB * 6 * plane);        // 4 B
    float* block_max = gmax + 16;                                       // 1024 floats

    sobel_init<<<dim3(4, 128, BB), 256, 0, stream>>>(x, tfA, mag, block_max);
    reduce_max<<<1, 256, 0, stream>>>(block_max, gmax);
    mag2em<<<dim3(BB * plane / 1024), 256, 0, stream>>>(mag, gmax);

    dim3 gv(4, HH / VSTRIP, BB);     // 1024 blocks
    dim3 gh(WW / 64, HH / 32, BB);   // 1024 blocks
    etf_v<<<gv, 256, 0, stream>>>(tfA, tfB, mag);
    etf_h<0><<<gh, 256, 0, stream>>>(tfB, (float*)tfA, mag);
    etf_v<<<gv, 256, 0, stream>>>(tfA, tfB, mag);
    etf_h<0><<<gh, 256, 0, stream>>>(tfB, (float*)tfA, mag);
    etf_v<<<gv, 256, 0, stream>>>(tfA, tfB, mag);
    etf_h<1><<<gh, 256, 0, stream>>>(tfB, (float*)d_out, mag);
}